// Round 2
// baseline (1441.450 us; speedup 1.0000x reference)
//
#include <hip/hip_runtime.h>
#include <hip/hip_bf16.h>
#include <math.h>

#define D_MODEL 1024
#define SEQ 2048
#define BATCH 8

typedef unsigned short u16;
typedef __attribute__((ext_vector_type(8))) short bf16x8;
typedef __attribute__((ext_vector_type(4))) float f32x4;

__device__ inline u16 f2bf(float f) {
  __hip_bfloat16 h = __float2bfloat16(f);
  return __builtin_bit_cast(u16, h);
}
__device__ inline float bf2f(u16 u) {
  return __builtin_bit_cast(float, (unsigned)u << 16);
}

// ---------------- LayerNorm: fp32 in -> bf16 out ----------------
__global__ __launch_bounds__(256) void ln_kernel(
    const float* __restrict__ x, const float* __restrict__ w,
    const float* __restrict__ b, u16* __restrict__ out) {
  int row = blockIdx.x;
  int t = threadIdx.x;
  const float4* xr = (const float4*)(x + (size_t)row * D_MODEL);
  float4 v = xr[t];
  float s = v.x + v.y + v.z + v.w;
  float s2 = v.x * v.x + v.y * v.y + v.z * v.z + v.w * v.w;
  for (int o = 32; o > 0; o >>= 1) {
    s += __shfl_down(s, o);
    s2 += __shfl_down(s2, o);
  }
  __shared__ float red[10];
  int wave = t >> 6, lane = t & 63;
  if (lane == 0) { red[wave] = s; red[4 + wave] = s2; }
  __syncthreads();
  if (t == 0) {
    float S = red[0] + red[1] + red[2] + red[3];
    float S2 = red[4] + red[5] + red[6] + red[7];
    float mu = S * (1.f / D_MODEL);
    float var = S2 * (1.f / D_MODEL) - mu * mu;
    red[8] = mu;
    red[9] = rsqrtf(var + 1e-5f);
  }
  __syncthreads();
  float mu = red[8], rstd = red[9];
  float4 w4 = ((const float4*)w)[t];
  float4 b4 = ((const float4*)b)[t];
  ushort4 o4;
  o4.x = f2bf((v.x - mu) * rstd * w4.x + b4.x);
  o4.y = f2bf((v.y - mu) * rstd * w4.y + b4.y);
  o4.z = f2bf((v.z - mu) * rstd * w4.z + b4.z);
  o4.w = f2bf((v.w - mu) * rstd * w4.w + b4.w);
  ((ushort4*)(out + (size_t)row * D_MODEL))[t] = o4;
}

// ---------------- LayerNorm: bf16 in -> bf16 out ----------------
__global__ __launch_bounds__(256) void ln_bf16_kernel(
    const u16* __restrict__ x, const float* __restrict__ w,
    const float* __restrict__ b, u16* __restrict__ out) {
  int row = blockIdx.x;
  int t = threadIdx.x;
  ushort4 q = ((const ushort4*)(x + (size_t)row * D_MODEL))[t];
  float v0 = bf2f(q.x), v1 = bf2f(q.y), v2 = bf2f(q.z), v3 = bf2f(q.w);
  float s = v0 + v1 + v2 + v3;
  float s2 = v0 * v0 + v1 * v1 + v2 * v2 + v3 * v3;
  for (int o = 32; o > 0; o >>= 1) {
    s += __shfl_down(s, o);
    s2 += __shfl_down(s2, o);
  }
  __shared__ float red[10];
  int wave = t >> 6, lane = t & 63;
  if (lane == 0) { red[wave] = s; red[4 + wave] = s2; }
  __syncthreads();
  if (t == 0) {
    float S = red[0] + red[1] + red[2] + red[3];
    float S2 = red[4] + red[5] + red[6] + red[7];
    float mu = S * (1.f / D_MODEL);
    float var = S2 * (1.f / D_MODEL) - mu * mu;
    red[8] = mu;
    red[9] = rsqrtf(var + 1e-5f);
  }
  __syncthreads();
  float mu = red[8], rstd = red[9];
  float4 w4 = ((const float4*)w)[t];
  float4 b4 = ((const float4*)b)[t];
  ushort4 o4;
  o4.x = f2bf((v0 - mu) * rstd * w4.x + b4.x);
  o4.y = f2bf((v1 - mu) * rstd * w4.y + b4.y);
  o4.z = f2bf((v2 - mu) * rstd * w4.z + b4.z);
  o4.w = f2bf((v3 - mu) * rstd * w4.w + b4.w);
  ((ushort4*)(out + (size_t)row * D_MODEL))[t] = o4;
}

// ---------------- Softmax over a 2048-wide fp32 row -> bf16 probs ----------------
__global__ __launch_bounds__(256) void softmax_kernel(
    const float* __restrict__ scores, u16* __restrict__ probs) {
  int row = blockIdx.x;
  int t = threadIdx.x;
  const float4* sr = (const float4*)(scores + (size_t)row * SEQ);
  float4 a = sr[2 * t], b = sr[2 * t + 1];
  float vals[8] = {a.x, a.y, a.z, a.w, b.x, b.y, b.z, b.w};
  float m = vals[0];
  for (int i = 1; i < 8; i++) m = fmaxf(m, vals[i]);
  for (int o = 32; o > 0; o >>= 1) m = fmaxf(m, __shfl_down(m, o));
  __shared__ float red[6];
  int wave = t >> 6, lane = t & 63;
  if (lane == 0) red[wave] = m;
  __syncthreads();
  if (t == 0) red[4] = fmaxf(fmaxf(red[0], red[1]), fmaxf(red[2], red[3]));
  __syncthreads();
  m = red[4];
  float s = 0.f;
  for (int i = 0; i < 8; i++) { vals[i] = __expf(vals[i] - m); s += vals[i]; }
  for (int o = 32; o > 0; o >>= 1) s += __shfl_down(s, o);
  if (lane == 0) red[wave] = s;
  __syncthreads();
  if (t == 0) red[5] = red[0] + red[1] + red[2] + red[3];
  __syncthreads();
  float inv = 1.f / red[5];
  union { u16 us[8]; int4 v4; } pk;
  for (int i = 0; i < 8; i++) pk.us[i] = f2bf(vals[i] * inv);
  ((int4*)(probs + (size_t)row * SEQ))[t] = pk.v4;
}

// ---------------- Transpose V slice of qkv (bf16): per batch [S,1024] -> [1024,S] ----
__global__ __launch_bounds__(256) void transpose_v(
    const u16* __restrict__ qkv, u16* __restrict__ vT) {
  int b = blockIdx.z;
  int s0 = blockIdx.x * 64, d0 = blockIdx.y * 64;
  __shared__ u16 tile[64][65];
  int t = threadIdx.x;
  for (int p = 0; p < 16; p++) {
    int idx = p * 256 + t;
    int r = idx >> 6, c = idx & 63;
    tile[r][c] = qkv[(size_t)(b * SEQ + s0 + r) * 3072 + 2 * D_MODEL + d0 + c];
  }
  __syncthreads();
  for (int p = 0; p < 16; p++) {
    int idx = p * 256 + t;
    int r = idx >> 6, c = idx & 63;
    vT[((size_t)b * D_MODEL + d0 + r) * SEQ + s0 + c] = tile[c][r];
  }
}

// ---------------- Weight fp32 [K,N] -> bf16 transposed [N,K] ----------------
__global__ __launch_bounds__(256) void wconv_t(
    const float* __restrict__ W, u16* __restrict__ Wt, int K, int N) {
  int k0 = blockIdx.x * 64, n0 = blockIdx.y * 64;
  __shared__ u16 tile[64][65];
  int t = threadIdx.x;
  for (int p = 0; p < 16; p++) {
    int idx = p * 256 + t;
    int r = idx >> 6, c = idx & 63;
    tile[r][c] = f2bf(W[(size_t)(k0 + r) * N + n0 + c]);
  }
  __syncthreads();
  for (int p = 0; p < 16; p++) {
    int idx = p * 256 + t;
    int r = idx >> 6, c = idx & 63;
    Wt[(size_t)(n0 + r) * K + k0 + c] = tile[c][r];
  }
}

// ---------------- GEMM: C[M,N] = A[M,K] * Bt[N,K]^T, bf16 in, fp32 acc ----------------
enum { EPI_BIAS_BF16 = 0, EPI_SCALE_F32 = 1, EPI_RESID_BF16 = 2,
       EPI_GELU_BF16 = 3, EPI_BIAS_F32 = 4 };

template <int EPI>
__global__ __launch_bounds__(256) void gemm_bt(
    const u16* __restrict__ A, const u16* __restrict__ Bt,
    void* __restrict__ Cv, const float* __restrict__ bias,
    const float* __restrict__ resid, int M, int N, int K,
    int lda, int ldb, int ldc, float scale) {
  constexpr int LDT = 40;  // padded LDS row stride (bf16 elems); 80B = 16B-aligned
  __shared__ __align__(16) u16 lA[128 * LDT];
  __shared__ __align__(16) u16 lB[128 * LDT];
  int t = threadIdx.x;
  int m0 = blockIdx.y * 128, n0 = blockIdx.x * 128;
  int wv = t >> 6, lane = t & 63;
  int wm = (wv >> 1) * 64, wn = (wv & 1) * 64;
  int lr = lane & 15, lq = lane >> 4;
  f32x4 acc[4][4] = {};

  int idx = t * 8;
  int sr = idx >> 5, sc = idx & 31;  // staging row/col within 128x32 tile

  for (int k0 = 0; k0 < K; k0 += 32) {
    *(int4*)(lA + sr * LDT + sc) =
        *(const int4*)(A + (size_t)(m0 + sr) * lda + k0 + sc);
    *(int4*)(lB + sr * LDT + sc) =
        *(const int4*)(Bt + (size_t)(n0 + sr) * ldb + k0 + sc);
    *(int4*)(lA + (sr + 64) * LDT + sc) =
        *(const int4*)(A + (size_t)(m0 + sr + 64) * lda + k0 + sc);
    *(int4*)(lB + (sr + 64) * LDT + sc) =
        *(const int4*)(Bt + (size_t)(n0 + sr + 64) * ldb + k0 + sc);
    __syncthreads();
    bf16x8 af[4], bfr[4];
    for (int i = 0; i < 4; i++)
      af[i] = *(const bf16x8*)(lA + (wm + i * 16 + lr) * LDT + lq * 8);
    for (int j = 0; j < 4; j++)
      bfr[j] = *(const bf16x8*)(lB + (wn + j * 16 + lr) * LDT + lq * 8);
    for (int i = 0; i < 4; i++)
      for (int j = 0; j < 4; j++)
        acc[i][j] = __builtin_amdgcn_mfma_f32_16x16x32_bf16(
            af[i], bfr[j], acc[i][j], 0, 0, 0);
    __syncthreads();
  }

  float* Cf = (float*)Cv;
  u16* Ch = (u16*)Cv;
  for (int i = 0; i < 4; i++) {
    for (int j = 0; j < 4; j++) {
      int col = n0 + wn + j * 16 + lr;
      float bcol = (EPI == EPI_BIAS_BF16 || EPI == EPI_GELU_BF16 ||
                    EPI == EPI_BIAS_F32) ? bias[col] : 0.f;
      for (int r = 0; r < 4; r++) {
        int row = m0 + wm + i * 16 + lq * 4 + r;
        float v = acc[i][j][r];
        size_t off = (size_t)row * ldc + col;
        if constexpr (EPI == EPI_BIAS_BF16) {
          Ch[off] = f2bf(v + bcol);
        } else if constexpr (EPI == EPI_SCALE_F32) {
          Cf[off] = v * scale;
        } else if constexpr (EPI == EPI_RESID_BF16) {
          Ch[off] = f2bf(v + resid[off]);
        } else if constexpr (EPI == EPI_GELU_BF16) {
          float xx = v + bcol;
          Ch[off] = f2bf(0.5f * xx * (1.f + erff(xx * 0.70710678118f)));
        } else {
          Cf[off] = v + bcol;
        }
      }
    }
  }
}

extern "C" void kernel_launch(void* const* d_in, const int* in_sizes, int n_in,
                              void* d_out, int out_size, void* d_ws, size_t ws_size,
                              hipStream_t stream) {
  const float* x      = (const float*)d_in[0];
  const float* ln1_w  = (const float*)d_in[1];
  const float* ln1_b  = (const float*)d_in[2];
  const float* W_attn = (const float*)d_in[3];
  const float* b_attn = (const float*)d_in[4];
  const float* ln2_w  = (const float*)d_in[5];
  const float* ln2_b  = (const float*)d_in[6];
  const float* W_fc   = (const float*)d_in[7];
  const float* b_fc   = (const float*)d_in[8];
  const float* W_proj = (const float*)d_in[9];
  const float* b_proj = (const float*)d_in[10];
  float* out = (float*)d_out;

  // Workspace layout (byte offsets). Peak = 216,006,656 B (~206 MiB).
  // Liveness overlays:
  //   [0,32M):   hb (LN1 out) -> vT (after QKV) -> hb again (LN2 out)
  //   [32M,128M): qkv -> fc (after LN2; fc spans [32M,160M))
  //   [128M,152M): sc(16M)+pr(8M), dead after attention (clobbered by fc)
  //   [152M,184M): pv = bf16(x + attn), dead after LN2 (head clobbered by fc)
  //   [184M,206M): bf16 transposed weights (live whole launch)
  if (ws_size < 216006656ull) return;  // diagnosable failure instead of OOB crash
  char* ws = (char*)d_ws;
  u16* hb   = (u16*)(ws + 0);
  u16* vT   = (u16*)(ws + 0);
  u16* qkv  = (u16*)(ws + 33554432ull);
  u16* fc   = (u16*)(ws + 33554432ull);
  float* sc = (float*)(ws + 134217728ull);
  u16* pr   = (u16*)(ws + 150994944ull);
  u16* pv   = (u16*)(ws + 159383552ull);
  u16* WaT  = (u16*)(ws + 192937984ull);
  u16* WfT  = (u16*)(ws + 199229440ull);
  u16* WpT  = (u16*)(ws + 207618048ull);

  // Weight conversion + transpose (fp32 [K,N] -> bf16 [N,K])
  wconv_t<<<dim3(1024 / 64, 3072 / 64), 256, 0, stream>>>(W_attn, WaT, 1024, 3072);
  wconv_t<<<dim3(1024 / 64, 4096 / 64), 256, 0, stream>>>(W_fc, WfT, 1024, 4096);
  wconv_t<<<dim3(4096 / 64, 1024 / 64), 256, 0, stream>>>(W_proj, WpT, 4096, 1024);

  // LN1: x -> hb (bf16)
  ln_kernel<<<BATCH * SEQ, 256, 0, stream>>>(x, ln1_w, ln1_b, hb);

  // QKV: [16384,1024] @ [1024,3072] + b -> bf16
  gemm_bt<EPI_BIAS_BF16><<<dim3(3072 / 128, (BATCH * SEQ) / 128), 256, 0, stream>>>(
      hb, WaT, qkv, b_attn, nullptr, BATCH * SEQ, 3072, 1024, 1024, 1024, 3072, 1.f);

  // V transpose per batch (vT overlays dead hb)
  transpose_v<<<dim3(SEQ / 64, D_MODEL / 64, BATCH), 256, 0, stream>>>(qkv, vT);

  // Attention, per batch
  const float iss = 0.03125f;  // 1/sqrt(1024)
  for (int b = 0; b < BATCH; b++) {
    const u16* qb = qkv + (size_t)b * SEQ * 3072;
    const u16* kb = qb + 1024;
    gemm_bt<EPI_SCALE_F32><<<dim3(SEQ / 128, SEQ / 128), 256, 0, stream>>>(
        qb, kb, sc, nullptr, nullptr, SEQ, SEQ, 1024, 3072, 3072, SEQ, iss);
    softmax_kernel<<<SEQ, 256, 0, stream>>>(sc, pr);
    gemm_bt<EPI_RESID_BF16><<<dim3(D_MODEL / 128, SEQ / 128), 256, 0, stream>>>(
        pr, vT + (size_t)b * D_MODEL * SEQ, pv + (size_t)b * SEQ * D_MODEL,
        nullptr, x + (size_t)b * SEQ * D_MODEL, SEQ, D_MODEL, SEQ,
        SEQ, SEQ, D_MODEL, 1.f);
  }

  // LN2: pv (bf16) -> hb (bf16, overlays dead vT)
  ln_bf16_kernel<<<BATCH * SEQ, 256, 0, stream>>>(pv, ln2_w, ln2_b, hb);

  // FC + GELU: [16384,1024] @ [1024,4096] -> bf16 (fc overlays dead qkv/sc/pr)
  gemm_bt<EPI_GELU_BF16><<<dim3(4096 / 128, (BATCH * SEQ) / 128), 256, 0, stream>>>(
      hb, WfT, fc, b_fc, nullptr, BATCH * SEQ, 4096, 1024, 1024, 1024, 4096, 1.f);

  // Proj: [16384,4096] @ [4096,1024] + b -> fp32 out
  gemm_bt<EPI_BIAS_F32><<<dim3(1024 / 128, (BATCH * SEQ) / 128), 256, 0, stream>>>(
      fc, WpT, out, b_proj, nullptr, BATCH * SEQ, 1024, 4096, 4096, 4096, 1024, 1.f);
}

// Round 3
// 1178.069 us; speedup vs baseline: 1.2236x; 1.2236x over previous
//
#include <hip/hip_runtime.h>
#include <hip/hip_bf16.h>
#include <math.h>

#define D_MODEL 1024
#define SEQ 2048
#define BATCH 8

typedef unsigned short u16;
typedef __attribute__((ext_vector_type(8))) short bf16x8;
typedef __attribute__((ext_vector_type(4))) float f32x4;

__device__ inline u16 f2bf(float f) {
  __hip_bfloat16 h = __float2bfloat16(f);
  return __builtin_bit_cast(u16, h);
}

// async 16B global->LDS copy; LDS dest is wave-uniform base + lane*16
__device__ __forceinline__ void async_cp16(const u16* g, u16* l) {
  __builtin_amdgcn_global_load_lds(
      (const __attribute__((address_space(1))) void*)g,
      (__attribute__((address_space(3))) void*)l, 16, 0, 0);
}

// ---------------- LayerNorm: fp32 in -> bf16 out ----------------
__global__ __launch_bounds__(256) void ln_kernel(
    const float* __restrict__ x, const float* __restrict__ w,
    const float* __restrict__ b, u16* __restrict__ out) {
  int row = blockIdx.x;
  int t = threadIdx.x;
  const float4* xr = (const float4*)(x + (size_t)row * D_MODEL);
  float4 v = xr[t];
  float s = v.x + v.y + v.z + v.w;
  float s2 = v.x * v.x + v.y * v.y + v.z * v.z + v.w * v.w;
  for (int o = 32; o > 0; o >>= 1) {
    s += __shfl_down(s, o);
    s2 += __shfl_down(s2, o);
  }
  __shared__ float red[10];
  int wave = t >> 6, lane = t & 63;
  if (lane == 0) { red[wave] = s; red[4 + wave] = s2; }
  __syncthreads();
  if (t == 0) {
    float S = red[0] + red[1] + red[2] + red[3];
    float S2 = red[4] + red[5] + red[6] + red[7];
    float mu = S * (1.f / D_MODEL);
    float var = S2 * (1.f / D_MODEL) - mu * mu;
    red[8] = mu;
    red[9] = rsqrtf(var + 1e-5f);
  }
  __syncthreads();
  float mu = red[8], rstd = red[9];
  float4 w4 = ((const float4*)w)[t];
  float4 b4 = ((const float4*)b)[t];
  ushort4 o4;
  o4.x = f2bf((v.x - mu) * rstd * w4.x + b4.x);
  o4.y = f2bf((v.y - mu) * rstd * w4.y + b4.y);
  o4.z = f2bf((v.z - mu) * rstd * w4.z + b4.z);
  o4.w = f2bf((v.w - mu) * rstd * w4.w + b4.w);
  ((ushort4*)(out + (size_t)row * D_MODEL))[t] = o4;
}

// ---- Softmax over 2048-wide fp32 row; bf16 probs written IN PLACE ----
// (probs occupy the first 4096 u16 slots of the row's 8KB; row stride 4096 u16)
__global__ __launch_bounds__(256) void softmax_kernel(float* __restrict__ scores) {
  int row = blockIdx.x;
  int t = threadIdx.x;
  const float4* sr = (const float4*)(scores + (size_t)row * SEQ);
  float4 a = sr[2 * t], b = sr[2 * t + 1];
  float vals[8] = {a.x, a.y, a.z, a.w, b.x, b.y, b.z, b.w};
  float m = vals[0];
  for (int i = 1; i < 8; i++) m = fmaxf(m, vals[i]);
  for (int o = 32; o > 0; o >>= 1) m = fmaxf(m, __shfl_down(m, o));
  __shared__ float red[6];
  int wave = t >> 6, lane = t & 63;
  if (lane == 0) red[wave] = m;
  __syncthreads();
  if (t == 0) red[4] = fmaxf(fmaxf(red[0], red[1]), fmaxf(red[2], red[3]));
  __syncthreads();
  m = red[4];
  float s = 0.f;
  for (int i = 0; i < 8; i++) { vals[i] = __expf(vals[i] - m); s += vals[i]; }
  for (int o = 32; o > 0; o >>= 1) s += __shfl_down(s, o);
  if (lane == 0) red[wave] = s;
  __syncthreads();
  if (t == 0) red[5] = red[0] + red[1] + red[2] + red[3];
  __syncthreads();
  float inv = 1.f / red[5];
  union { u16 us[8]; int4 v4; } pk;
  for (int i = 0; i < 8; i++) pk.us[i] = f2bf(vals[i] * inv);
  u16* probs = (u16*)scores;
  // all reads of this row happened before the first __syncthreads -> safe in-place
  ((int4*)(probs + (size_t)row * 4096))[t] = pk.v4;
}

// ---- Transpose V slice of qkv (bf16): per batch [S,1024] -> [1024,S] ----
__global__ __launch_bounds__(256) void transpose_v(
    const u16* __restrict__ qkv, u16* __restrict__ vT) {
  int b = blockIdx.z;
  int s0 = blockIdx.x * 64, d0 = blockIdx.y * 64;
  __shared__ u16 tile[64][65];
  int t = threadIdx.x;
  for (int p = 0; p < 16; p++) {
    int idx = p * 256 + t;
    int r = idx >> 6, c = idx & 63;
    tile[r][c] = qkv[(size_t)(b * SEQ + s0 + r) * 3072 + 2 * D_MODEL + d0 + c];
  }
  __syncthreads();
  for (int p = 0; p < 16; p++) {
    int idx = p * 256 + t;
    int r = idx >> 6, c = idx & 63;
    vT[((size_t)b * D_MODEL + d0 + r) * SEQ + s0 + c] = tile[c][r];
  }
}

// ---------------- Weight fp32 [K,N] -> bf16 transposed [N,K] ----------------
__global__ __launch_bounds__(256) void wconv_t(
    const float* __restrict__ W, u16* __restrict__ Wt, int K, int N) {
  int k0 = blockIdx.x * 64, n0 = blockIdx.y * 64;
  __shared__ u16 tile[64][65];
  int t = threadIdx.x;
  for (int p = 0; p < 16; p++) {
    int idx = p * 256 + t;
    int r = idx >> 6, c = idx & 63;
    tile[r][c] = f2bf(W[(size_t)(k0 + r) * N + n0 + c]);
  }
  __syncthreads();
  for (int p = 0; p < 16; p++) {
    int idx = p * 256 + t;
    int r = idx >> 6, c = idx & 63;
    Wt[(size_t)(n0 + r) * K + k0 + c] = tile[c][r];
  }
}

// ---- GEMM: C[M,N] = A[M,K] * Bt[N,K]^T, bf16 in, fp32 acc, async LDS staging ----
enum { EPI_BIAS_BF16 = 0, EPI_SCALE_F32 = 1, EPI_RESID_F32 = 2,
       EPI_GELU_BF16 = 3, EPI_BIAS_F32 = 4 };

template <int EPI>
__global__ __launch_bounds__(256) void gemm_bt(
    const u16* __restrict__ A, const u16* __restrict__ Bt,
    void* __restrict__ Cv, const float* __restrict__ bias,
    const float* __restrict__ resid, int M, int N, int K,
    int lda, int ldb, int ldc, float scale,
    long long saB, long long sbB, long long scB, long long srB) {
  // unpadded [128][32] bf16 tiles — layout dictated by global_load_lds
  __shared__ __align__(16) u16 lA[128 * 32];
  __shared__ __align__(16) u16 lB[128 * 32];
  int t = threadIdx.x;
  int zb = blockIdx.z;
  A += (size_t)zb * saB;
  Bt += (size_t)zb * sbB;
  int m0 = blockIdx.y * 128, n0 = blockIdx.x * 128;
  int wv = t >> 6, lane = t & 63;

  // staging: wave wv covers rows [wv*16, wv*16+16) and [64+wv*16, ...)
  // lane i -> row base + i/4, col (i%4)*8  (matches base + lane*16 in LDS)
  int srow = (wv << 4) + (lane >> 2);
  int scol = (lane & 3) << 3;
  const u16* gA0 = A + (size_t)(m0 + srow) * lda + scol;
  const u16* gA1 = A + (size_t)(m0 + 64 + srow) * lda + scol;
  const u16* gB0 = Bt + (size_t)(n0 + srow) * ldb + scol;
  const u16* gB1 = Bt + (size_t)(n0 + 64 + srow) * ldb + scol;
  u16* lA0 = lA + (wv << 9);
  u16* lA1 = lA + ((wv + 4) << 9);
  u16* lB0 = lB + (wv << 9);
  u16* lB1 = lB + ((wv + 4) << 9);

  int wm = (wv >> 1) * 64, wn = (wv & 1) * 64;
  int lr = lane & 15, lq = lane >> 4;
  f32x4 acc[4][4] = {};

  for (int k0 = 0; k0 < K; k0 += 32) {
    async_cp16(gA0, lA0);
    async_cp16(gA1, lA1);
    async_cp16(gB0, lB0);
    async_cp16(gB1, lB1);
    gA0 += 32; gA1 += 32; gB0 += 32; gB1 += 32;
    __syncthreads();  // drains vmcnt -> staging complete for all waves
    bf16x8 af[4], bfr[4];
    for (int i = 0; i < 4; i++)
      af[i] = *(const bf16x8*)(lA + (wm + i * 16 + lr) * 32 + lq * 8);
    for (int j = 0; j < 4; j++)
      bfr[j] = *(const bf16x8*)(lB + (wn + j * 16 + lr) * 32 + lq * 8);
    for (int i = 0; i < 4; i++)
      for (int j = 0; j < 4; j++)
        acc[i][j] = __builtin_amdgcn_mfma_f32_16x16x32_bf16(
            af[i], bfr[j], acc[i][j], 0, 0, 0);
    __syncthreads();  // protect LDS from next iteration's staging
  }

  float* Cf = (float*)Cv + (size_t)zb * scB;
  u16* Ch = (u16*)Cv + (size_t)zb * scB;
  const float* rz = resid + (size_t)zb * srB;
  for (int i = 0; i < 4; i++) {
    for (int j = 0; j < 4; j++) {
      int col = n0 + wn + j * 16 + lr;
      float bcol = (EPI == EPI_BIAS_BF16 || EPI == EPI_GELU_BF16 ||
                    EPI == EPI_BIAS_F32) ? bias[col] : 0.f;
      for (int r = 0; r < 4; r++) {
        int row = m0 + wm + i * 16 + lq * 4 + r;
        float v = acc[i][j][r];
        size_t off = (size_t)row * ldc + col;
        if constexpr (EPI == EPI_BIAS_BF16) {
          Ch[off] = f2bf(v + bcol);
        } else if constexpr (EPI == EPI_SCALE_F32) {
          Cf[off] = v * scale;
        } else if constexpr (EPI == EPI_RESID_F32) {
          Cf[off] = v + rz[off];
        } else if constexpr (EPI == EPI_GELU_BF16) {
          float xx = v + bcol;
          Ch[off] = f2bf(0.5f * xx * (1.f + erff(xx * 0.70710678118f)));
        } else {
          Cf[off] = v + bcol;
        }
      }
    }
  }
}

extern "C" void kernel_launch(void* const* d_in, const int* in_sizes, int n_in,
                              void* d_out, int out_size, void* d_ws, size_t ws_size,
                              hipStream_t stream) {
  const float* x      = (const float*)d_in[0];
  const float* ln1_w  = (const float*)d_in[1];
  const float* ln1_b  = (const float*)d_in[2];
  const float* W_attn = (const float*)d_in[3];
  const float* b_attn = (const float*)d_in[4];
  const float* ln2_w  = (const float*)d_in[5];
  const float* ln2_b  = (const float*)d_in[6];
  const float* W_fc   = (const float*)d_in[7];
  const float* b_fc   = (const float*)d_in[8];
  const float* W_proj = (const float*)d_in[9];
  const float* b_proj = (const float*)d_in[10];
  float* out = (float*)d_out;

  // Workspace layout, peak 190,840,832 B (~182 MiB):
  //   [0,32M):    hb (LN1 out) -> vT (after QKV) -> hb (LN2 out)
  //   [32M,128M): qkv -> fc (fc spans [32M,160M), after qkv/sc dead)
  //   [128M,160M): sc fp32 scores, 2 batches/chunk; probs bf16 in-place
  //   [160M,182M): bf16 transposed weights (live whole launch)
  // Residual (x + attn) is stored fp32 directly in d_out (dead until Proj).
  if (ws_size < 190840832ull) return;
  char* ws = (char*)d_ws;
  u16* hb   = (u16*)(ws + 0);
  u16* vT   = (u16*)(ws + 0);
  u16* qkv  = (u16*)(ws + 33554432ull);
  u16* fc   = (u16*)(ws + 33554432ull);
  float* sc = (float*)(ws + 134217728ull);
  u16* WaT  = (u16*)(ws + 167772160ull);
  u16* WfT  = (u16*)(ws + 174063616ull);
  u16* WpT  = (u16*)(ws + 182452224ull);

  wconv_t<<<dim3(1024 / 64, 3072 / 64), 256, 0, stream>>>(W_attn, WaT, 1024, 3072);
  wconv_t<<<dim3(1024 / 64, 4096 / 64), 256, 0, stream>>>(W_fc, WfT, 1024, 4096);
  wconv_t<<<dim3(4096 / 64, 1024 / 64), 256, 0, stream>>>(W_proj, WpT, 4096, 1024);

  ln_kernel<<<BATCH * SEQ, 256, 0, stream>>>(x, ln1_w, ln1_b, hb);

  // QKV: [16384,1024] @ [1024,3072] + b -> bf16
  gemm_bt<EPI_BIAS_BF16><<<dim3(24, 128, 1), 256, 0, stream>>>(
      hb, WaT, qkv, b_attn, x, BATCH * SEQ, 3072, 1024, 1024, 1024, 3072, 1.f,
      0, 0, 0, 0);

  transpose_v<<<dim3(SEQ / 64, D_MODEL / 64, BATCH), 256, 0, stream>>>(qkv, vT);

  // Attention in 4 chunks of 2 batches, batched over gridDim.z
  const float iss = 0.03125f;  // 1/sqrt(1024)
  for (int c = 0; c < 4; c++) {
    const u16* qb = qkv + (size_t)c * 2 * SEQ * 3072;
    gemm_bt<EPI_SCALE_F32><<<dim3(16, 16, 2), 256, 0, stream>>>(
        qb, qb + 1024, sc, nullptr, x, SEQ, SEQ, 1024, 3072, 3072, SEQ, iss,
        (long long)SEQ * 3072, (long long)SEQ * 3072, (long long)SEQ * SEQ, 0);
    softmax_kernel<<<2 * SEQ, 256, 0, stream>>>(sc);
    gemm_bt<EPI_RESID_F32><<<dim3(8, 16, 2), 256, 0, stream>>>(
        (const u16*)sc, vT + (size_t)c * 2 * D_MODEL * SEQ,
        out + (size_t)c * 2 * SEQ * D_MODEL, nullptr,
        x + (size_t)c * 2 * SEQ * D_MODEL, SEQ, D_MODEL, SEQ,
        4096, SEQ, D_MODEL, 1.f,
        (long long)SEQ * 4096, (long long)D_MODEL * SEQ,
        (long long)SEQ * D_MODEL, (long long)SEQ * D_MODEL);
  }

  // LN2: out (fp32 residual) -> hb
  ln_kernel<<<BATCH * SEQ, 256, 0, stream>>>(out, ln2_w, ln2_b, hb);

  // FC + GELU: [16384,1024] @ [1024,4096] -> bf16
  gemm_bt<EPI_GELU_BF16><<<dim3(32, 128, 1), 256, 0, stream>>>(
      hb, WfT, fc, b_fc, x, BATCH * SEQ, 4096, 1024, 1024, 1024, 4096, 1.f,
      0, 0, 0, 0);

  // Proj: [16384,4096] @ [4096,1024] + b -> fp32 out
  gemm_bt<EPI_BIAS_F32><<<dim3(8, 128, 1), 256, 0, stream>>>(
      fc, WpT, out, b_proj, x, BATCH * SEQ, 1024, 4096, 4096, 4096, 1024, 1.f,
      0, 0, 0, 0);
}

// Round 4
// 885.372 us; speedup vs baseline: 1.6281x; 1.3306x over previous
//
#include <hip/hip_runtime.h>
#include <hip/hip_bf16.h>
#include <math.h>

#define D_MODEL 1024
#define SEQ 2048
#define BATCH 8

typedef unsigned short u16;
typedef __attribute__((ext_vector_type(8))) short bf16x8;
typedef __attribute__((ext_vector_type(4))) float f32x4;

__device__ inline u16 f2bf(float f) {
  __hip_bfloat16 h = __float2bfloat16(f);
  return __builtin_bit_cast(u16, h);
}
__device__ inline float bf2f(u16 u) {
  return __builtin_bit_cast(float, (unsigned)u << 16);
}

// async 16B global->LDS copy; LDS dest is wave-uniform base + lane*16
__device__ __forceinline__ void async_cp16(const u16* g, u16* l) {
  __builtin_amdgcn_global_load_lds(
      (const __attribute__((address_space(1))) void*)g,
      (__attribute__((address_space(3))) void*)l, 16, 0, 0);
}

// ---------------- LayerNorm: fp32 in -> bf16 out ----------------
__global__ __launch_bounds__(256) void ln_kernel(
    const float* __restrict__ x, const float* __restrict__ w,
    const float* __restrict__ b, u16* __restrict__ out) {
  int row = blockIdx.x;
  int t = threadIdx.x;
  const float4* xr = (const float4*)(x + (size_t)row * D_MODEL);
  float4 v = xr[t];
  float s = v.x + v.y + v.z + v.w;
  float s2 = v.x * v.x + v.y * v.y + v.z * v.z + v.w * v.w;
  for (int o = 32; o > 0; o >>= 1) {
    s += __shfl_down(s, o);
    s2 += __shfl_down(s2, o);
  }
  __shared__ float red[10];
  int wave = t >> 6, lane = t & 63;
  if (lane == 0) { red[wave] = s; red[4 + wave] = s2; }
  __syncthreads();
  if (t == 0) {
    float S = red[0] + red[1] + red[2] + red[3];
    float S2 = red[4] + red[5] + red[6] + red[7];
    float mu = S * (1.f / D_MODEL);
    float var = S2 * (1.f / D_MODEL) - mu * mu;
    red[8] = mu;
    red[9] = rsqrtf(var + 1e-5f);
  }
  __syncthreads();
  float mu = red[8], rstd = red[9];
  float4 w4 = ((const float4*)w)[t];
  float4 b4 = ((const float4*)b)[t];
  ushort4 o4;
  o4.x = f2bf((v.x - mu) * rstd * w4.x + b4.x);
  o4.y = f2bf((v.y - mu) * rstd * w4.y + b4.y);
  o4.z = f2bf((v.z - mu) * rstd * w4.z + b4.z);
  o4.w = f2bf((v.w - mu) * rstd * w4.w + b4.w);
  ((ushort4*)(out + (size_t)row * D_MODEL))[t] = o4;
}

// ---- Softmax over a 2048-wide bf16 row, IN PLACE (fp32 math) ----
__global__ __launch_bounds__(256) void softmax_bf16_kernel(u16* __restrict__ p) {
  int row = blockIdx.x;
  int t = threadIdx.x;
  int4 q = ((const int4*)(p + (size_t)row * SEQ))[t];
  u16 us[8];
  __builtin_memcpy(us, &q, 16);
  float vals[8];
  for (int i = 0; i < 8; i++) vals[i] = bf2f(us[i]);
  float m = vals[0];
  for (int i = 1; i < 8; i++) m = fmaxf(m, vals[i]);
  for (int o = 32; o > 0; o >>= 1) m = fmaxf(m, __shfl_down(m, o));
  __shared__ float red[6];
  int wave = t >> 6, lane = t & 63;
  if (lane == 0) red[wave] = m;
  __syncthreads();
  if (t == 0) red[4] = fmaxf(fmaxf(red[0], red[1]), fmaxf(red[2], red[3]));
  __syncthreads();
  m = red[4];
  float s = 0.f;
  for (int i = 0; i < 8; i++) { vals[i] = __expf(vals[i] - m); s += vals[i]; }
  for (int o = 32; o > 0; o >>= 1) s += __shfl_down(s, o);
  if (lane == 0) red[wave] = s;
  __syncthreads();
  if (t == 0) red[5] = red[0] + red[1] + red[2] + red[3];
  __syncthreads();
  float inv = 1.f / red[5];
  union { u16 us[8]; int4 v4; } pk;
  for (int i = 0; i < 8; i++) pk.us[i] = f2bf(vals[i] * inv);
  // each thread rewrites exactly the bytes it read; one block per row -> safe
  ((int4*)(p + (size_t)row * SEQ))[t] = pk.v4;
}

// ---- Transpose V slice of qkv (bf16): per batch [S,1024] -> [1024,S] ----
__global__ __launch_bounds__(256) void transpose_v(
    const u16* __restrict__ qkv, u16* __restrict__ vT) {
  int b = blockIdx.z;
  int s0 = blockIdx.x * 64, d0 = blockIdx.y * 64;
  __shared__ u16 tile[64][65];
  int t = threadIdx.x;
  for (int p = 0; p < 16; p++) {
    int idx = p * 256 + t;
    int r = idx >> 6, c = idx & 63;
    tile[r][c] = qkv[(size_t)(b * SEQ + s0 + r) * 3072 + 2 * D_MODEL + d0 + c];
  }
  __syncthreads();
  for (int p = 0; p < 16; p++) {
    int idx = p * 256 + t;
    int r = idx >> 6, c = idx & 63;
    vT[((size_t)b * D_MODEL + d0 + r) * SEQ + s0 + c] = tile[c][r];
  }
}

// ---------------- Weight fp32 [K,N] -> bf16 transposed [N,K] ----------------
__global__ __launch_bounds__(256) void wconv_t(
    const float* __restrict__ W, u16* __restrict__ Wt, int K, int N) {
  int k0 = blockIdx.x * 64, n0 = blockIdx.y * 64;
  __shared__ u16 tile[64][65];
  int t = threadIdx.x;
  for (int p = 0; p < 16; p++) {
    int idx = p * 256 + t;
    int r = idx >> 6, c = idx & 63;
    tile[r][c] = f2bf(W[(size_t)(k0 + r) * N + n0 + c]);
  }
  __syncthreads();
  for (int p = 0; p < 16; p++) {
    int idx = p * 256 + t;
    int r = idx >> 6, c = idx & 63;
    Wt[(size_t)(n0 + r) * K + k0 + c] = tile[c][r];
  }
}

// ---- GEMM: C[M,N] = A[M,K] * Bt[N,K]^T, bf16 in, fp32 acc, async LDS staging ----
enum { EPI_BIAS_BF16 = 0, EPI_SCALE_BF16 = 1, EPI_RESID_F32 = 2,
       EPI_GELU_BF16 = 3, EPI_BIAS_F32 = 4 };

template <int EPI>
__global__ __launch_bounds__(256, 3) void gemm_bt(
    const u16* __restrict__ A, const u16* __restrict__ Bt,
    void* __restrict__ Cv, const float* __restrict__ bias,
    const float* __restrict__ resid, int M, int N, int K,
    int lda, int ldb, int ldc, float scale,
    long long saB, long long sbB, long long scB, long long srB) {
  // unpadded [128][32] bf16 tiles — layout dictated by global_load_lds
  __shared__ __align__(16) u16 lA[128 * 32];
  __shared__ __align__(16) u16 lB[128 * 32];
  int t = threadIdx.x;
  int zb = blockIdx.z;
  A += (size_t)zb * saB;
  Bt += (size_t)zb * sbB;

  // tile-raster swizzle: 4 M-tiles per stripe, N fastest within stripe.
  // (all grids here have M-tiles % 4 == 0)
  int gx = gridDim.x;
  int flat = blockIdx.x + gx * blockIdx.y;
  int rem = flat % (4 * gx);
  int m0 = ((flat / (4 * gx)) * 4 + (rem & 3)) * 128;
  int n0 = (rem >> 2) * 128;

  int wv = t >> 6, lane = t & 63;
  // staging: wave wv covers rows [wv*16, wv*16+16) and [64+wv*16, ...)
  int srow = (wv << 4) + (lane >> 2);
  int scol = (lane & 3) << 3;
  const u16* gA0 = A + (size_t)(m0 + srow) * lda + scol;
  const u16* gA1 = A + (size_t)(m0 + 64 + srow) * lda + scol;
  const u16* gB0 = Bt + (size_t)(n0 + srow) * ldb + scol;
  const u16* gB1 = Bt + (size_t)(n0 + 64 + srow) * ldb + scol;
  u16* lA0 = lA + (wv << 9);
  u16* lA1 = lA + ((wv + 4) << 9);
  u16* lB0 = lB + (wv << 9);
  u16* lB1 = lB + ((wv + 4) << 9);

  int wm = (wv >> 1) * 64, wn = (wv & 1) * 64;
  int lr = lane & 15, lq = lane >> 4;
  f32x4 acc[4][4] = {};

  for (int k0 = 0; k0 < K; k0 += 32) {
    async_cp16(gA0, lA0);
    async_cp16(gA1, lA1);
    async_cp16(gB0, lB0);
    async_cp16(gB1, lB1);
    gA0 += 32; gA1 += 32; gB0 += 32; gB1 += 32;
    __syncthreads();
    bf16x8 af[4], bfr[4];
    for (int i = 0; i < 4; i++)
      af[i] = *(const bf16x8*)(lA + (wm + i * 16 + lr) * 32 + lq * 8);
    for (int j = 0; j < 4; j++)
      bfr[j] = *(const bf16x8*)(lB + (wn + j * 16 + lr) * 32 + lq * 8);
    for (int i = 0; i < 4; i++)
      for (int j = 0; j < 4; j++)
        acc[i][j] = __builtin_amdgcn_mfma_f32_16x16x32_bf16(
            af[i], bfr[j], acc[i][j], 0, 0, 0);
    __syncthreads();
  }

  float* Cf = (float*)Cv + (size_t)zb * scB;
  u16* Ch = (u16*)Cv + (size_t)zb * scB;
  const float* rz = resid + (size_t)zb * srB;
  for (int i = 0; i < 4; i++) {
    for (int j = 0; j < 4; j++) {
      int col = n0 + wn + j * 16 + lr;
      float bcol = (EPI == EPI_BIAS_BF16 || EPI == EPI_GELU_BF16 ||
                    EPI == EPI_BIAS_F32) ? bias[col] : 0.f;
      for (int r = 0; r < 4; r++) {
        int row = m0 + wm + i * 16 + lq * 4 + r;
        float v = acc[i][j][r];
        size_t off = (size_t)row * ldc + col;
        if constexpr (EPI == EPI_BIAS_BF16) {
          Ch[off] = f2bf(v + bcol);
        } else if constexpr (EPI == EPI_SCALE_BF16) {
          Ch[off] = f2bf(v * scale);
        } else if constexpr (EPI == EPI_RESID_F32) {
          Cf[off] = v + rz[off];
        } else if constexpr (EPI == EPI_GELU_BF16) {
          float xx = v + bcol;
          Ch[off] = f2bf(0.5f * xx * (1.f + erff(xx * 0.70710678118f)));
        } else {
          Cf[off] = v + bcol;
        }
      }
    }
  }
}

extern "C" void kernel_launch(void* const* d_in, const int* in_sizes, int n_in,
                              void* d_out, int out_size, void* d_ws, size_t ws_size,
                              hipStream_t stream) {
  const float* x      = (const float*)d_in[0];
  const float* ln1_w  = (const float*)d_in[1];
  const float* ln1_b  = (const float*)d_in[2];
  const float* W_attn = (const float*)d_in[3];
  const float* b_attn = (const float*)d_in[4];
  const float* ln2_w  = (const float*)d_in[5];
  const float* ln2_b  = (const float*)d_in[6];
  const float* W_fc   = (const float*)d_in[7];
  const float* b_fc   = (const float*)d_in[8];
  const float* W_proj = (const float*)d_in[9];
  const float* b_proj = (const float*)d_in[10];
  float* out = (float*)d_out;

  // Workspace layout, peak 190,840,832 B (~182 MiB):
  //   [0,32M):    hb (LN1 out) -> vT (after QKV) -> hb (LN2 out)
  //   [32M,128M): qkv -> fc (fc spans [32M,160M), after qkv/sc dead)
  //   [128M,160M): sc bf16 scores, 4 batches/chunk; softmax in-place
  //   [160M,182M): bf16 transposed weights (live whole launch)
  // Residual (x + attn) is stored fp32 directly in d_out (dead until Proj).
  if (ws_size < 190840832ull) return;
  char* ws = (char*)d_ws;
  u16* hb   = (u16*)(ws + 0);
  u16* vT   = (u16*)(ws + 0);
  u16* qkv  = (u16*)(ws + 33554432ull);
  u16* fc   = (u16*)(ws + 33554432ull);
  u16* sc   = (u16*)(ws + 134217728ull);
  u16* WaT  = (u16*)(ws + 167772160ull);
  u16* WfT  = (u16*)(ws + 174063616ull);
  u16* WpT  = (u16*)(ws + 182452224ull);

  wconv_t<<<dim3(1024 / 64, 3072 / 64), 256, 0, stream>>>(W_attn, WaT, 1024, 3072);
  wconv_t<<<dim3(1024 / 64, 4096 / 64), 256, 0, stream>>>(W_fc, WfT, 1024, 4096);
  wconv_t<<<dim3(4096 / 64, 1024 / 64), 256, 0, stream>>>(W_proj, WpT, 4096, 1024);

  ln_kernel<<<BATCH * SEQ, 256, 0, stream>>>(x, ln1_w, ln1_b, hb);

  // QKV: [16384,1024] @ [1024,3072] + b -> bf16
  gemm_bt<EPI_BIAS_BF16><<<dim3(24, 128, 1), 256, 0, stream>>>(
      hb, WaT, qkv, b_attn, x, BATCH * SEQ, 3072, 1024, 1024, 1024, 3072, 1.f,
      0, 0, 0, 0);

  transpose_v<<<dim3(SEQ / 64, D_MODEL / 64, BATCH), 256, 0, stream>>>(qkv, vT);

  // Attention in 2 chunks of 4 batches, batched over gridDim.z
  const float iss = 0.03125f;  // 1/sqrt(1024)
  for (int c = 0; c < 2; c++) {
    const u16* qb = qkv + (size_t)c * 4 * SEQ * 3072;
    gemm_bt<EPI_SCALE_BF16><<<dim3(16, 16, 4), 256, 0, stream>>>(
        qb, qb + 1024, sc, nullptr, x, SEQ, SEQ, 1024, 3072, 3072, SEQ, iss,
        (long long)SEQ * 3072, (long long)SEQ * 3072, (long long)SEQ * SEQ, 0);
    softmax_bf16_kernel<<<4 * SEQ, 256, 0, stream>>>(sc);
    gemm_bt<EPI_RESID_F32><<<dim3(8, 16, 4), 256, 0, stream>>>(
        sc, vT + (size_t)c * 4 * D_MODEL * SEQ,
        out + (size_t)c * 4 * SEQ * D_MODEL, nullptr,
        x + (size_t)c * 4 * SEQ * D_MODEL, SEQ, D_MODEL, SEQ,
        SEQ, SEQ, D_MODEL, 1.f,
        (long long)SEQ * SEQ, (long long)D_MODEL * SEQ,
        (long long)SEQ * D_MODEL, (long long)SEQ * D_MODEL);
  }

  // LN2: out (fp32 residual) -> hb
  ln_kernel<<<BATCH * SEQ, 256, 0, stream>>>(out, ln2_w, ln2_b, hb);

  // FC + GELU: [16384,1024] @ [1024,4096] -> bf16
  gemm_bt<EPI_GELU_BF16><<<dim3(32, 128, 1), 256, 0, stream>>>(
      hb, WfT, fc, b_fc, x, BATCH * SEQ, 4096, 1024, 1024, 1024, 4096, 1.f,
      0, 0, 0, 0);

  // Proj: [16384,4096] @ [4096,1024] + b -> fp32 out
  gemm_bt<EPI_BIAS_F32><<<dim3(8, 128, 1), 256, 0, stream>>>(
      fc, WpT, out, b_proj, x, BATCH * SEQ, 1024, 4096, 4096, 4096, 1024, 1.f,
      0, 0, 0, 0);
}

// Round 5
// 864.655 us; speedup vs baseline: 1.6671x; 1.0240x over previous
//
#include <hip/hip_runtime.h>
#include <hip/hip_bf16.h>
#include <math.h>

#define D_MODEL 1024
#define SEQ 2048
#define BATCH 8

typedef unsigned short u16;
typedef __attribute__((ext_vector_type(8))) short bf16x8;
typedef __attribute__((ext_vector_type(4))) float f32x4;

__device__ inline u16 f2bf(float f) {
  __hip_bfloat16 h = __float2bfloat16(f);
  return __builtin_bit_cast(u16, h);
}
__device__ inline float bf2f(u16 u) {
  return __builtin_bit_cast(float, (unsigned)u << 16);
}

// async 16B global->LDS copy; LDS dest is wave-uniform base + lane*16
__device__ __forceinline__ void async_cp16(const u16* g, u16* l) {
  __builtin_amdgcn_global_load_lds(
      (const __attribute__((address_space(1))) void*)g,
      (__attribute__((address_space(3))) void*)l, 16, 0, 0);
}

// ---------------- LayerNorm: fp32 in -> bf16 out ----------------
__global__ __launch_bounds__(256) void ln_kernel(
    const float* __restrict__ x, const float* __restrict__ w,
    const float* __restrict__ b, u16* __restrict__ out) {
  int row = blockIdx.x;
  int t = threadIdx.x;
  const float4* xr = (const float4*)(x + (size_t)row * D_MODEL);
  float4 v = xr[t];
  float s = v.x + v.y + v.z + v.w;
  float s2 = v.x * v.x + v.y * v.y + v.z * v.z + v.w * v.w;
  for (int o = 32; o > 0; o >>= 1) {
    s += __shfl_down(s, o);
    s2 += __shfl_down(s2, o);
  }
  __shared__ float red[10];
  int wave = t >> 6, lane = t & 63;
  if (lane == 0) { red[wave] = s; red[4 + wave] = s2; }
  __syncthreads();
  if (t == 0) {
    float S = red[0] + red[1] + red[2] + red[3];
    float S2 = red[4] + red[5] + red[6] + red[7];
    float mu = S * (1.f / D_MODEL);
    float var = S2 * (1.f / D_MODEL) - mu * mu;
    red[8] = mu;
    red[9] = rsqrtf(var + 1e-5f);
  }
  __syncthreads();
  float mu = red[8], rstd = red[9];
  float4 w4 = ((const float4*)w)[t];
  float4 b4 = ((const float4*)b)[t];
  ushort4 o4;
  o4.x = f2bf((v.x - mu) * rstd * w4.x + b4.x);
  o4.y = f2bf((v.y - mu) * rstd * w4.y + b4.y);
  o4.z = f2bf((v.z - mu) * rstd * w4.z + b4.z);
  o4.w = f2bf((v.w - mu) * rstd * w4.w + b4.w);
  ((ushort4*)(out + (size_t)row * D_MODEL))[t] = o4;
}

// ---- Softmax over a 2048-wide bf16 row, IN PLACE (fp32 math) ----
__global__ __launch_bounds__(256) void softmax_bf16_kernel(u16* __restrict__ p) {
  int row = blockIdx.x;
  int t = threadIdx.x;
  int4 q = ((const int4*)(p + (size_t)row * SEQ))[t];
  u16 us[8];
  __builtin_memcpy(us, &q, 16);
  float vals[8];
  for (int i = 0; i < 8; i++) vals[i] = bf2f(us[i]);
  float m = vals[0];
  for (int i = 1; i < 8; i++) m = fmaxf(m, vals[i]);
  for (int o = 32; o > 0; o >>= 1) m = fmaxf(m, __shfl_down(m, o));
  __shared__ float red[6];
  int wave = t >> 6, lane = t & 63;
  if (lane == 0) red[wave] = m;
  __syncthreads();
  if (t == 0) red[4] = fmaxf(fmaxf(red[0], red[1]), fmaxf(red[2], red[3]));
  __syncthreads();
  m = red[4];
  float s = 0.f;
  for (int i = 0; i < 8; i++) { vals[i] = __expf(vals[i] - m); s += vals[i]; }
  for (int o = 32; o > 0; o >>= 1) s += __shfl_down(s, o);
  if (lane == 0) red[wave] = s;
  __syncthreads();
  if (t == 0) red[5] = red[0] + red[1] + red[2] + red[3];
  __syncthreads();
  float inv = 1.f / red[5];
  union { u16 us[8]; int4 v4; } pk;
  for (int i = 0; i < 8; i++) pk.us[i] = f2bf(vals[i] * inv);
  ((int4*)(p + (size_t)row * SEQ))[t] = pk.v4;
}

// ---------------- Weight fp32 [K,N] -> bf16 transposed [N,K] ----------------
__global__ __launch_bounds__(256) void wconv_t(
    const float* __restrict__ W, u16* __restrict__ Wt, int K, int N) {
  int k0 = blockIdx.x * 64, n0 = blockIdx.y * 64;
  __shared__ u16 tile[64][65];
  int t = threadIdx.x;
  for (int p = 0; p < 16; p++) {
    int idx = p * 256 + t;
    int r = idx >> 6, c = idx & 63;
    tile[r][c] = f2bf(W[(size_t)(k0 + r) * N + n0 + c]);
  }
  __syncthreads();
  for (int p = 0; p < 16; p++) {
    int idx = p * 256 + t;
    int r = idx >> 6, c = idx & 63;
    Wt[(size_t)(n0 + r) * K + k0 + c] = tile[c][r];
  }
}

// ---- GEMM: C[M,N] = A[M,K] * Bt[N,K]^T, bf16 in, fp32 acc, async LDS staging ----
// EPI_QKV: cols <2048 -> qk buffer (ldc=2048); cols >=2048 -> vT[b][d][s] transposed
enum { EPI_QKV = 0, EPI_SCALE_BF16 = 1, EPI_RESID_F32 = 2,
       EPI_GELU_BF16 = 3, EPI_BIAS_F32 = 4 };

template <int EPI>
__global__ __launch_bounds__(256, 4) void gemm_bt(
    const u16* __restrict__ A, const u16* __restrict__ Bt,
    void* __restrict__ Cv, const float* __restrict__ bias,
    const float* __restrict__ resid, u16* __restrict__ vTp,
    int M, int N, int K, int lda, int ldb, int ldc, float scale,
    long long saB, long long sbB, long long scB, long long srB) {
  __shared__ __align__(16) u16 lA[128 * 32];
  __shared__ __align__(16) u16 lB[128 * 32];
  int t = threadIdx.x;
  int zb = blockIdx.z;
  A += (size_t)zb * saB;
  Bt += (size_t)zb * sbB;

  // tile-raster swizzle: 4 M-tiles per stripe, N fastest within stripe.
  int gx = gridDim.x;
  int flat = blockIdx.x + gx * blockIdx.y;
  int rem = flat % (4 * gx);
  int m0 = ((flat / (4 * gx)) * 4 + (rem & 3)) * 128;
  int n0 = (rem >> 2) * 128;

  int wv = t >> 6, lane = t & 63;
  int srow = (wv << 4) + (lane >> 2);
  int scol = (lane & 3) << 3;
  const u16* gA0 = A + (size_t)(m0 + srow) * lda + scol;
  const u16* gA1 = A + (size_t)(m0 + 64 + srow) * lda + scol;
  const u16* gB0 = Bt + (size_t)(n0 + srow) * ldb + scol;
  const u16* gB1 = Bt + (size_t)(n0 + 64 + srow) * ldb + scol;
  u16* lA0 = lA + (wv << 9);
  u16* lA1 = lA + ((wv + 4) << 9);
  u16* lB0 = lB + (wv << 9);
  u16* lB1 = lB + ((wv + 4) << 9);

  int wm = (wv >> 1) * 64, wn = (wv & 1) * 64;
  int lr = lane & 15, lq = lane >> 4;
  f32x4 acc[4][4] = {};

  for (int k0 = 0; k0 < K; k0 += 32) {
    async_cp16(gA0, lA0);
    async_cp16(gA1, lA1);
    async_cp16(gB0, lB0);
    async_cp16(gB1, lB1);
    gA0 += 32; gA1 += 32; gB0 += 32; gB1 += 32;
    __syncthreads();
    bf16x8 af[4], bfr[4];
    for (int i = 0; i < 4; i++)
      af[i] = *(const bf16x8*)(lA + (wm + i * 16 + lr) * 32 + lq * 8);
    for (int j = 0; j < 4; j++)
      bfr[j] = *(const bf16x8*)(lB + (wn + j * 16 + lr) * 32 + lq * 8);
    for (int i = 0; i < 4; i++)
      for (int j = 0; j < 4; j++)
        acc[i][j] = __builtin_amdgcn_mfma_f32_16x16x32_bf16(
            af[i], bfr[j], acc[i][j], 0, 0, 0);
    __syncthreads();
  }

  float* Cf = (float*)Cv + (size_t)zb * scB;
  u16* Ch = (u16*)Cv + (size_t)zb * scB;
  const float* rz = resid + (size_t)zb * srB;

  if constexpr (EPI == EPI_QKV) {
    if (n0 >= 2048) {
      // V columns: write transposed vT[b][d][s], 4 consecutive s per lane
      for (int i = 0; i < 4; i++) {
        int row0 = m0 + wm + i * 16 + lq * 4;
        int batch = row0 >> 11, s0 = row0 & 2047;
        for (int j = 0; j < 4; j++) {
          int d = n0 - 2048 + wn + j * 16 + lr;
          float bcol = bias[n0 + wn + j * 16 + lr];
          ushort4 o4;
          o4.x = f2bf(acc[i][j][0] + bcol);
          o4.y = f2bf(acc[i][j][1] + bcol);
          o4.z = f2bf(acc[i][j][2] + bcol);
          o4.w = f2bf(acc[i][j][3] + bcol);
          *(ushort4*)(vTp + (((size_t)batch * 1024 + d) << 11) + s0) = o4;
        }
      }
      return;
    }
  }

  for (int i = 0; i < 4; i++) {
    for (int j = 0; j < 4; j++) {
      int col = n0 + wn + j * 16 + lr;
      float bcol = (EPI == EPI_QKV || EPI == EPI_GELU_BF16 ||
                    EPI == EPI_BIAS_F32) ? bias[col] : 0.f;
      for (int r = 0; r < 4; r++) {
        int row = m0 + wm + i * 16 + lq * 4 + r;
        float v = acc[i][j][r];
        size_t off = (size_t)row * ldc + col;
        if constexpr (EPI == EPI_QKV) {
          Ch[off] = f2bf(v + bcol);
        } else if constexpr (EPI == EPI_SCALE_BF16) {
          Ch[off] = f2bf(v * scale);
        } else if constexpr (EPI == EPI_RESID_F32) {
          Cf[off] = v + rz[off];
        } else if constexpr (EPI == EPI_GELU_BF16) {
          float xx = v + bcol;
          // tanh-approx GELU: ~10 VALU ops vs ~30+ for erff
          float u = xx * (0.7978845608f + 0.0356774081f * xx * xx);
          float e = __expf(2.f * u);
          float th = 1.f - 2.f * __builtin_amdgcn_rcpf(e + 1.f);
          Ch[off] = f2bf(0.5f * xx * (1.f + th));
        } else {
          Cf[off] = v + bcol;
        }
      }
    }
  }
}

extern "C" void kernel_launch(void* const* d_in, const int* in_sizes, int n_in,
                              void* d_out, int out_size, void* d_ws, size_t ws_size,
                              hipStream_t stream) {
  const float* x      = (const float*)d_in[0];
  const float* ln1_w  = (const float*)d_in[1];
  const float* ln1_b  = (const float*)d_in[2];
  const float* W_attn = (const float*)d_in[3];
  const float* b_attn = (const float*)d_in[4];
  const float* ln2_w  = (const float*)d_in[5];
  const float* ln2_b  = (const float*)d_in[6];
  const float* W_fc   = (const float*)d_in[7];
  const float* b_fc   = (const float*)d_in[8];
  const float* W_proj = (const float*)d_in[9];
  const float* b_proj = (const float*)d_in[10];
  float* out = (float*)d_out;

  // Workspace layout, peak 190,840,832 B (~182 MiB):
  //   [0,32M):    hb (LN1 out, later LN2 out)
  //   [32M,96M):  qk bf16 [16384,2048] (q cols 0..1023, k cols 1024..2047)
  //   [96M,128M): vT bf16 [8][1024][2048] (written transposed by QKV epilogue)
  //   [128M,160M): sc bf16 scores, 4 batches/chunk; softmax in-place
  //   fc [32M,160M) overlays qk+vT+sc after attention completes
  //   [160M,182M): bf16 transposed weights (live whole launch)
  // Residual (x + attn) lives fp32 in d_out until Proj overwrites it.
  if (ws_size < 190840832ull) return;
  char* ws = (char*)d_ws;
  u16* hb   = (u16*)(ws + 0);
  u16* qk   = (u16*)(ws + 33554432ull);
  u16* vT   = (u16*)(ws + 100663296ull);
  u16* sc   = (u16*)(ws + 134217728ull);
  u16* fc   = (u16*)(ws + 33554432ull);
  u16* WaT  = (u16*)(ws + 167772160ull);
  u16* WfT  = (u16*)(ws + 174063616ull);
  u16* WpT  = (u16*)(ws + 182452224ull);

  wconv_t<<<dim3(1024 / 64, 3072 / 64), 256, 0, stream>>>(W_attn, WaT, 1024, 3072);
  wconv_t<<<dim3(1024 / 64, 4096 / 64), 256, 0, stream>>>(W_fc, WfT, 1024, 4096);
  wconv_t<<<dim3(4096 / 64, 1024 / 64), 256, 0, stream>>>(W_proj, WpT, 4096, 1024);

  ln_kernel<<<BATCH * SEQ, 256, 0, stream>>>(x, ln1_w, ln1_b, hb);

  // QKV: [16384,1024] @ [1024,3072] + b; q,k -> qk (ldc 2048), v -> vT transposed
  gemm_bt<EPI_QKV><<<dim3(24, 128, 1), 256, 0, stream>>>(
      hb, WaT, qk, b_attn, x, vT, BATCH * SEQ, 3072, 1024, 1024, 1024, 2048, 1.f,
      0, 0, 0, 0);

  // Attention in 2 chunks of 4 batches, batched over gridDim.z
  const float iss = 0.03125f;  // 1/sqrt(1024)
  for (int c = 0; c < 2; c++) {
    const u16* qb = qk + (size_t)c * 4 * SEQ * 2048;
    gemm_bt<EPI_SCALE_BF16><<<dim3(16, 16, 4), 256, 0, stream>>>(
        qb, qb + 1024, sc, nullptr, x, nullptr, SEQ, SEQ, 1024, 2048, 2048, SEQ,
        iss, (long long)SEQ * 2048, (long long)SEQ * 2048, (long long)SEQ * SEQ, 0);
    softmax_bf16_kernel<<<4 * SEQ, 256, 0, stream>>>(sc);
    gemm_bt<EPI_RESID_F32><<<dim3(8, 16, 4), 256, 0, stream>>>(
        sc, vT + (size_t)c * 4 * D_MODEL * SEQ,
        out + (size_t)c * 4 * SEQ * D_MODEL, nullptr,
        x + (size_t)c * 4 * SEQ * D_MODEL, nullptr, SEQ, D_MODEL, SEQ,
        SEQ, SEQ, D_MODEL, 1.f,
        (long long)SEQ * SEQ, (long long)D_MODEL * SEQ,
        (long long)SEQ * D_MODEL, (long long)SEQ * D_MODEL);
  }

  // LN2: out (fp32 residual) -> hb
  ln_kernel<<<BATCH * SEQ, 256, 0, stream>>>(out, ln2_w, ln2_b, hb);

  // FC + GELU: [16384,1024] @ [1024,4096] -> bf16
  gemm_bt<EPI_GELU_BF16><<<dim3(32, 128, 1), 256, 0, stream>>>(
      hb, WfT, fc, b_fc, x, nullptr, BATCH * SEQ, 4096, 1024, 1024, 1024, 4096,
      1.f, 0, 0, 0, 0);

  // Proj: [16384,4096] @ [4096,1024] + b -> fp32 out
  gemm_bt<EPI_BIAS_F32><<<dim3(8, 128, 1), 256, 0, stream>>>(
      fc, WpT, out, b_proj, x, nullptr, BATCH * SEQ, 1024, 4096, 4096, 4096,
      1024, 1.f, 0, 0, 0, 0);
}

// Round 6
// 767.639 us; speedup vs baseline: 1.8778x; 1.1264x over previous
//
#include <hip/hip_runtime.h>
#include <hip/hip_bf16.h>
#include <math.h>

#define D_MODEL 1024
#define SEQ 2048
#define BATCH 8

typedef unsigned short u16;
typedef __attribute__((ext_vector_type(8))) short bf16x8;
typedef __attribute__((ext_vector_type(4))) float f32x4;

__device__ inline u16 f2bf(float f) {
  __hip_bfloat16 h = __float2bfloat16(f);
  return __builtin_bit_cast(u16, h);
}
__device__ inline float bf2f(u16 u) {
  return __builtin_bit_cast(float, (unsigned)u << 16);
}

// async 16B global->LDS copy; LDS dest is wave-uniform base + lane*16
__device__ __forceinline__ void async_cp16(const u16* g, u16* l) {
  __builtin_amdgcn_global_load_lds(
      (const __attribute__((address_space(1))) void*)g,
      (__attribute__((address_space(3))) void*)l, 16, 0, 0);
}

// ---------------- LayerNorm: fp32 in -> bf16 out ----------------
__global__ __launch_bounds__(256) void ln_kernel(
    const float* __restrict__ x, const float* __restrict__ w,
    const float* __restrict__ b, u16* __restrict__ out) {
  int row = blockIdx.x;
  int t = threadIdx.x;
  const float4* xr = (const float4*)(x + (size_t)row * D_MODEL);
  float4 v = xr[t];
  float s = v.x + v.y + v.z + v.w;
  float s2 = v.x * v.x + v.y * v.y + v.z * v.z + v.w * v.w;
  for (int o = 32; o > 0; o >>= 1) {
    s += __shfl_down(s, o);
    s2 += __shfl_down(s2, o);
  }
  __shared__ float red[10];
  int wave = t >> 6, lane = t & 63;
  if (lane == 0) { red[wave] = s; red[4 + wave] = s2; }
  __syncthreads();
  if (t == 0) {
    float S = red[0] + red[1] + red[2] + red[3];
    float S2 = red[4] + red[5] + red[6] + red[7];
    float mu = S * (1.f / D_MODEL);
    float var = S2 * (1.f / D_MODEL) - mu * mu;
    red[8] = mu;
    red[9] = rsqrtf(var + 1e-5f);
  }
  __syncthreads();
  float mu = red[8], rstd = red[9];
  float4 w4 = ((const float4*)w)[t];
  float4 b4 = ((const float4*)b)[t];
  ushort4 o4;
  o4.x = f2bf((v.x - mu) * rstd * w4.x + b4.x);
  o4.y = f2bf((v.y - mu) * rstd * w4.y + b4.y);
  o4.z = f2bf((v.z - mu) * rstd * w4.z + b4.z);
  o4.w = f2bf((v.w - mu) * rstd * w4.w + b4.w);
  ((ushort4*)(out + (size_t)row * D_MODEL))[t] = o4;
}

// ---- Softmax over a 2048-wide bf16 row, IN PLACE (fp32 math) ----
__global__ __launch_bounds__(256) void softmax_bf16_kernel(u16* __restrict__ p) {
  int row = blockIdx.x;
  int t = threadIdx.x;
  int4 q = ((const int4*)(p + (size_t)row * SEQ))[t];
  u16 us[8];
  __builtin_memcpy(us, &q, 16);
  float vals[8];
  for (int i = 0; i < 8; i++) vals[i] = bf2f(us[i]);
  float m = vals[0];
  for (int i = 1; i < 8; i++) m = fmaxf(m, vals[i]);
  for (int o = 32; o > 0; o >>= 1) m = fmaxf(m, __shfl_down(m, o));
  __shared__ float red[6];
  int wave = t >> 6, lane = t & 63;
  if (lane == 0) red[wave] = m;
  __syncthreads();
  if (t == 0) red[4] = fmaxf(fmaxf(red[0], red[1]), fmaxf(red[2], red[3]));
  __syncthreads();
  m = red[4];
  float s = 0.f;
  for (int i = 0; i < 8; i++) { vals[i] = __expf(vals[i] - m); s += vals[i]; }
  for (int o = 32; o > 0; o >>= 1) s += __shfl_down(s, o);
  if (lane == 0) red[wave] = s;
  __syncthreads();
  if (t == 0) red[5] = red[0] + red[1] + red[2] + red[3];
  __syncthreads();
  float inv = 1.f / red[5];
  union { u16 us[8]; int4 v4; } pk;
  for (int i = 0; i < 8; i++) pk.us[i] = f2bf(vals[i] * inv);
  ((int4*)(p + (size_t)row * SEQ))[t] = pk.v4;
}

// ---------------- Weight fp32 [K,N] -> bf16 transposed [N,K] ----------------
__global__ __launch_bounds__(256) void wconv_t(
    const float* __restrict__ W, u16* __restrict__ Wt, int K, int N) {
  int k0 = blockIdx.x * 64, n0 = blockIdx.y * 64;
  __shared__ u16 tile[64][65];
  int t = threadIdx.x;
  for (int p = 0; p < 16; p++) {
    int idx = p * 256 + t;
    int r = idx >> 6, c = idx & 63;
    tile[r][c] = f2bf(W[(size_t)(k0 + r) * N + n0 + c]);
  }
  __syncthreads();
  for (int p = 0; p < 16; p++) {
    int idx = p * 256 + t;
    int r = idx >> 6, c = idx & 63;
    Wt[(size_t)(n0 + r) * K + k0 + c] = tile[c][r];
  }
}

// ---- GEMM: C[M,N] = A[M,K] * Bt[N,K]^T, bf16 in, fp32 acc ----
// BK=64, async LDS staging, XOR bank-conflict swizzle.
// LDS tile [128][64] u16; physical col-group (16B) = logical ^ (row & 7).
enum { EPI_QKV = 0, EPI_SCALE_BF16 = 1, EPI_RESID_F32 = 2,
       EPI_GELU_BF16 = 3, EPI_BIAS_F32 = 4 };

template <int EPI>
__global__ __launch_bounds__(256, 4) void gemm_bt(
    const u16* __restrict__ A, const u16* __restrict__ Bt,
    void* __restrict__ Cv, const float* __restrict__ bias,
    const float* __restrict__ resid, u16* __restrict__ vTp,
    int M, int N, int K, int lda, int ldb, int ldc, float scale,
    long long saB, long long sbB, long long scB, long long srB) {
  __shared__ __align__(16) u16 lA[128 * 64];
  __shared__ __align__(16) u16 lB[128 * 64];
  int t = threadIdx.x;
  int zb = blockIdx.z;
  A += (size_t)zb * saB;
  Bt += (size_t)zb * sbB;

  // tile-raster swizzle: 4 M-tiles per stripe, N fastest within stripe.
  int gx = gridDim.x;
  int flat = blockIdx.x + gx * blockIdx.y;
  int rem = flat % (4 * gx);
  int m0 = ((flat / (4 * gx)) * 4 + (rem & 3)) * 128;
  int n0 = (rem >> 2) * 128;

  int wv = t >> 6, lane = t & 63;

  // staging: 4 rounds per tile; round r covers rows r*32 + t/8, thread t
  // fetches global col-group (t&7) ^ ((t>>3)&7)  (XOR swizzle, key = row&7,
  // r*32 == 0 mod 8 so key is r-independent); LDS dest = r*2048 + t*8 u16.
  int srow = t >> 3;                       // 0..31
  int scg = (t & 7) ^ ((t >> 3) & 7);      // swizzled col-group
  int scol = scg << 3;                     // u16 offset within row
  const u16* gA = A + (size_t)(m0 + srow) * lda + scol;
  const u16* gB = Bt + (size_t)(n0 + srow) * ldb + scol;
  u16* lAd = lA + t * 8;
  u16* lBd = lB + t * 8;

  int wm = (wv >> 1) * 64, wn = (wv & 1) * 64;
  int lr = lane & 15, lq = lane >> 4;
  int keyr = lr & 7;                       // fragment-read swizzle key
  f32x4 acc[4][4] = {};

  for (int k0 = 0; k0 < K; k0 += 64) {
    #pragma unroll
    for (int r = 0; r < 4; r++) {
      async_cp16(gA + (size_t)(r * 32) * lda, lAd + r * 2048);
      async_cp16(gB + (size_t)(r * 32) * ldb, lBd + r * 2048);
    }
    gA += 64; gB += 64;
    __syncthreads();
    #pragma unroll
    for (int ks = 0; ks < 2; ks++) {
      bf16x8 af[4], bfr[4];
      #pragma unroll
      for (int i = 0; i < 4; i++)
        af[i] = *(const bf16x8*)(lA + (wm + i * 16 + lr) * 64 +
                                 (((lq + 4 * ks) ^ keyr) << 3));
      #pragma unroll
      for (int j = 0; j < 4; j++)
        bfr[j] = *(const bf16x8*)(lB + (wn + j * 16 + lr) * 64 +
                                  (((lq + 4 * ks) ^ keyr) << 3));
      #pragma unroll
      for (int i = 0; i < 4; i++)
        #pragma unroll
        for (int j = 0; j < 4; j++)
          acc[i][j] = __builtin_amdgcn_mfma_f32_16x16x32_bf16(
              af[i], bfr[j], acc[i][j], 0, 0, 0);
    }
    __syncthreads();
  }

  float* Cf = (float*)Cv + (size_t)zb * scB;
  u16* Ch = (u16*)Cv + (size_t)zb * scB;
  const float* rz = resid + (size_t)zb * srB;

  if constexpr (EPI == EPI_QKV) {
    if (n0 >= 2048) {
      // V columns: write transposed vT[b][d][s], 4 consecutive s per lane
      for (int i = 0; i < 4; i++) {
        int row0 = m0 + wm + i * 16 + lq * 4;
        int batch = row0 >> 11, s0 = row0 & 2047;
        for (int j = 0; j < 4; j++) {
          int d = n0 - 2048 + wn + j * 16 + lr;
          float bcol = bias[n0 + wn + j * 16 + lr];
          ushort4 o4;
          o4.x = f2bf(acc[i][j][0] + bcol);
          o4.y = f2bf(acc[i][j][1] + bcol);
          o4.z = f2bf(acc[i][j][2] + bcol);
          o4.w = f2bf(acc[i][j][3] + bcol);
          *(ushort4*)(vTp + (((size_t)batch * 1024 + d) << 11) + s0) = o4;
        }
      }
      return;
    }
  }

  for (int i = 0; i < 4; i++) {
    for (int j = 0; j < 4; j++) {
      int col = n0 + wn + j * 16 + lr;
      float bcol = (EPI == EPI_QKV || EPI == EPI_GELU_BF16 ||
                    EPI == EPI_BIAS_F32) ? bias[col] : 0.f;
      for (int r = 0; r < 4; r++) {
        int row = m0 + wm + i * 16 + lq * 4 + r;
        float v = acc[i][j][r];
        size_t off = (size_t)row * ldc + col;
        if constexpr (EPI == EPI_QKV) {
          Ch[off] = f2bf(v + bcol);
        } else if constexpr (EPI == EPI_SCALE_BF16) {
          Ch[off] = f2bf(v * scale);
        } else if constexpr (EPI == EPI_RESID_F32) {
          Cf[off] = v + rz[off];
        } else if constexpr (EPI == EPI_GELU_BF16) {
          float xx = v + bcol;
          // tanh-approx GELU
          float u = xx * (0.7978845608f + 0.0356774081f * xx * xx);
          float e = __expf(2.f * u);
          float th = 1.f - 2.f * __builtin_amdgcn_rcpf(e + 1.f);
          Ch[off] = f2bf(0.5f * xx * (1.f + th));
        } else {
          Cf[off] = v + bcol;
        }
      }
    }
  }
}

extern "C" void kernel_launch(void* const* d_in, const int* in_sizes, int n_in,
                              void* d_out, int out_size, void* d_ws, size_t ws_size,
                              hipStream_t stream) {
  const float* x      = (const float*)d_in[0];
  const float* ln1_w  = (const float*)d_in[1];
  const float* ln1_b  = (const float*)d_in[2];
  const float* W_attn = (const float*)d_in[3];
  const float* b_attn = (const float*)d_in[4];
  const float* ln2_w  = (const float*)d_in[5];
  const float* ln2_b  = (const float*)d_in[6];
  const float* W_fc   = (const float*)d_in[7];
  const float* b_fc   = (const float*)d_in[8];
  const float* W_proj = (const float*)d_in[9];
  const float* b_proj = (const float*)d_in[10];
  float* out = (float*)d_out;

  // Workspace layout, peak 190,840,832 B (~182 MiB):
  //   [0,32M):    hb (LN1 out, later LN2 out)
  //   [32M,96M):  qk bf16 [16384,2048] (q cols 0..1023, k cols 1024..2047)
  //   [96M,128M): vT bf16 [8][1024][2048] (written transposed by QKV epilogue)
  //   [128M,160M): sc bf16 scores, 4 batches/chunk; softmax in-place
  //   fc [32M,160M) overlays qk+vT+sc after attention completes
  //   [160M,182M): bf16 transposed weights (live whole launch)
  // Residual (x + attn) lives fp32 in d_out until Proj overwrites it.
  if (ws_size < 190840832ull) return;
  char* ws = (char*)d_ws;
  u16* hb   = (u16*)(ws + 0);
  u16* qk   = (u16*)(ws + 33554432ull);
  u16* vT   = (u16*)(ws + 100663296ull);
  u16* sc   = (u16*)(ws + 134217728ull);
  u16* fc   = (u16*)(ws + 33554432ull);
  u16* WaT  = (u16*)(ws + 167772160ull);
  u16* WfT  = (u16*)(ws + 174063616ull);
  u16* WpT  = (u16*)(ws + 182452224ull);

  wconv_t<<<dim3(1024 / 64, 3072 / 64), 256, 0, stream>>>(W_attn, WaT, 1024, 3072);
  wconv_t<<<dim3(1024 / 64, 4096 / 64), 256, 0, stream>>>(W_fc, WfT, 1024, 4096);
  wconv_t<<<dim3(4096 / 64, 1024 / 64), 256, 0, stream>>>(W_proj, WpT, 4096, 1024);

  ln_kernel<<<BATCH * SEQ, 256, 0, stream>>>(x, ln1_w, ln1_b, hb);

  // QKV: [16384,1024] @ [1024,3072] + b; q,k -> qk (ldc 2048), v -> vT transposed
  gemm_bt<EPI_QKV><<<dim3(24, 128, 1), 256, 0, stream>>>(
      hb, WaT, qk, b_attn, x, vT, BATCH * SEQ, 3072, 1024, 1024, 1024, 2048, 1.f,
      0, 0, 0, 0);

  // Attention in 2 chunks of 4 batches, batched over gridDim.z
  const float iss = 0.03125f;  // 1/sqrt(1024)
  for (int c = 0; c < 2; c++) {
    const u16* qb = qk + (size_t)c * 4 * SEQ * 2048;
    gemm_bt<EPI_SCALE_BF16><<<dim3(16, 16, 4), 256, 0, stream>>>(
        qb, qb + 1024, sc, nullptr, x, nullptr, SEQ, SEQ, 1024, 2048, 2048, SEQ,
        iss, (long long)SEQ * 2048, (long long)SEQ * 2048, (long long)SEQ * SEQ, 0);
    softmax_bf16_kernel<<<4 * SEQ, 256, 0, stream>>>(sc);
    gemm_bt<EPI_RESID_F32><<<dim3(8, 16, 4), 256, 0, stream>>>(
        sc, vT + (size_t)c * 4 * D_MODEL * SEQ,
        out + (size_t)c * 4 * SEQ * D_MODEL, nullptr,
        x + (size_t)c * 4 * SEQ * D_MODEL, nullptr, SEQ, D_MODEL, SEQ,
        SEQ, SEQ, D_MODEL, 1.f,
        (long long)SEQ * SEQ, (long long)D_MODEL * SEQ,
        (long long)SEQ * D_MODEL, (long long)SEQ * D_MODEL);
  }

  // LN2: out (fp32 residual) -> hb
  ln_kernel<<<BATCH * SEQ, 256, 0, stream>>>(out, ln2_w, ln2_b, hb);

  // FC + GELU: [16384,1024] @ [1024,4096] -> bf16
  gemm_bt<EPI_GELU_BF16><<<dim3(32, 128, 1), 256, 0, stream>>>(
      hb, WfT, fc, b_fc, x, nullptr, BATCH * SEQ, 4096, 1024, 1024, 1024, 4096,
      1.f, 0, 0, 0, 0);

  // Proj: [16384,4096] @ [4096,1024] + b -> fp32 out
  gemm_bt<EPI_BIAS_F32><<<dim3(8, 128, 1), 256, 0, stream>>>(
      fc, WpT, out, b_proj, x, nullptr, BATCH * SEQ, 1024, 4096, 4096, 4096,
      1024, 1.f, 0, 0, 0, 0);
}